// Round 5
// baseline (200.296 us; speedup 1.0000x reference)
//
#include <hip/hip_runtime.h>

// GLA forward, chunked. T=2048, B=8, IN=512, DV=512, NK=128, CHUNK=128, NCH=16.
// Round 5: proj_mfma double-buffered staging (1 barrier/iter, prefetch tile
// k+1 during compute of tile k); scan_cp re-gridded (128x128) + unroll-4
// batched loads. Rest unchanged from round 4.
//
// Layouts (cb = c*8+b, r = t_glob*8+b):
//   a_buf  fp32 [r][128]
//   k_raw/q_raw bf16 [r][128]
//   qb/kbs bf16 [r][128]          (q~ = q*cp, k~ = k/(cp+eps))
//   kt     bf16 [cb*128 + n][s]   (k~ transposed)
//   vt     bf16 [cb*512 + d][s]
//   Gt     bf16 [cb*512 + d][n]   (scan input, overlays xb)
//   St     bf16 [cb*512 + d][n]   (S_prev per chunk)

#define EPSV 1e-8f

typedef __bf16 bf16x8 __attribute__((ext_vector_type(8)));
typedef float f32x4 __attribute__((ext_vector_type(4)));

__device__ __forceinline__ void async_copy16(const void* g, void* l) {
  __builtin_amdgcn_global_load_lds(
      (const __attribute__((address_space(1))) void*)g,
      (__attribute__((address_space(3))) void*)l, 16, 0, 0);
}

// ---- fp32 -> bf16 conversion (8 elems/thread) ----
__global__ __launch_bounds__(256) void conv_bf16(const float* __restrict__ src,
                                                 __bf16* __restrict__ dst) {
  long i = ((long)blockIdx.x * 256 + threadIdx.x) * 8;
  float4 f0 = *(const float4*)(src + i);
  float4 f1 = *(const float4*)(src + i + 4);
  bf16x8 h;
  h[0] = (__bf16)f0.x; h[1] = (__bf16)f0.y; h[2] = (__bf16)f0.z; h[3] = (__bf16)f0.w;
  h[4] = (__bf16)f1.x; h[5] = (__bf16)f1.y; h[6] = (__bf16)f1.z; h[7] = (__bf16)f1.w;
  *(bf16x8*)(dst + i) = h;
}

// ---- concat Wv|Wk|Wq|Wa into bf16 [896][512] ----
__global__ __launch_bounds__(256) void conv_w(const float* __restrict__ Wv,
                                              const float* __restrict__ Wk,
                                              const float* __restrict__ Wq,
                                              const float* __restrict__ Wa,
                                              __bf16* __restrict__ dst) {
  long i = ((long)blockIdx.x * 256 + threadIdx.x) * 8;
  int row = (int)(i >> 9);
  int col = (int)(i & 511);
  const float* src;
  if (row < 512)      src = Wv + (long)row * 512 + col;
  else if (row < 640) src = Wk + (long)(row - 512) * 512 + col;
  else if (row < 768) src = Wq + (long)(row - 640) * 512 + col;
  else                src = Wa + (long)(row - 768) * 512 + col;
  float4 f0 = *(const float4*)(src);
  float4 f1 = *(const float4*)(src + 4);
  bf16x8 h;
  h[0] = (__bf16)f0.x; h[1] = (__bf16)f0.y; h[2] = (__bf16)f0.z; h[3] = (__bf16)f0.w;
  h[4] = (__bf16)f1.x; h[5] = (__bf16)f1.y; h[6] = (__bf16)f1.z; h[7] = (__bf16)f1.w;
  *(bf16x8*)(dst + i) = h;
}

// ---- K1: projection GEMM, bf16 MFMA, double-buffered staging ----
// grid (128 Mtiles, 7 Ntiles). nt 0..3 -> vt (LDS-transposed); 4 k; 5 q; 6 alpha.
__global__ __launch_bounds__(256) void proj_mfma(
    const __bf16* __restrict__ xb, const __bf16* __restrict__ wcat,
    const float* __restrict__ bv, const float* __restrict__ bk,
    const float* __restrict__ bq, const float* __restrict__ ba,
    __bf16* __restrict__ vt, __bf16* __restrict__ kout,
    __bf16* __restrict__ qout, float* __restrict__ aout) {
  // 34816 B. dbuf layout: [a0:4096][b0:4096][a1:4096][b1:4096] (bf16 elems)
  // tr (transpose buffer, 128*136 bf16) reuses the whole block post-loop.
  __shared__ __attribute__((aligned(16))) char smem[128 * 136 * 2];
  __bf16* sm = (__bf16*)smem;
  __bf16* tr = (__bf16*)smem;

  int tid = threadIdx.x;
  int lane = tid & 63, wave = tid >> 6;
  int mt = blockIdx.x, nt = blockIdx.y;
  int wr = wave >> 1, wcol = wave & 1;

  const __bf16* xtile = xb + (long)mt * 128 * 512;
  const __bf16* wtile = wcat + (long)nt * 128 * 512;

  f32x4 acc[4][4] = {};
  int lr = lane >> 2, lc = lane & 3;
  int l15 = lane & 15, qd = lane >> 4;

  // stage tile (k0) into buffer sel
  auto stage = [&](int k0, int sel) {
    __bf16* asm_ = sm + sel * 8192;
    __bf16* bsm_ = sm + sel * 8192 + 4096;
#pragma unroll
    for (int h = 0; h < 2; ++h) {
      int q = wave * 2 + h;              // 1KB chunk = 16 rows of 128x32 tile
      int row = q * 16 + lr;
      async_copy16(xtile + (long)row * 512 + k0 + lc * 8, &asm_[q * 512]);
      async_copy16(wtile + (long)row * 512 + k0 + lc * 8, &bsm_[q * 512]);
    }
  };

  stage(0, 0);
  for (int it = 0; it < 16; ++it) {
    __syncthreads();                     // tile `it` published (vmcnt+lgkm drain)
    int sel = it & 1;
    if (it < 15) stage((it + 1) * 32, sel ^ 1);  // prefetch overlaps compute
    const __bf16* asm_ = sm + sel * 8192;
    const __bf16* bsm_ = sm + sel * 8192 + 4096;
    bf16x8 af[4], bfr[4];
#pragma unroll
    for (int t = 0; t < 4; ++t) {
      af[t]  = *(const bf16x8*)&asm_[(wr * 64 + t * 16 + l15) * 32 + qd * 8];
      bfr[t] = *(const bf16x8*)&bsm_[(wcol * 64 + t * 16 + l15) * 32 + qd * 8];
    }
#pragma unroll
    for (int i = 0; i < 4; ++i)
#pragma unroll
      for (int j = 0; j < 4; ++j)
        acc[i][j] = __builtin_amdgcn_mfma_f32_16x16x32_bf16(af[i], bfr[j], acc[i][j], 0, 0, 0);
  }

  if (nt < 4) {
    __syncthreads();                     // all frag reads done before tr reuse
    // v path: bias, cast bf16, transpose in LDS, write vt.
    // tr layout: [d(128)][b*16 + t_l] pitch 136.
    const float* bias = bv + nt * 128;
#pragma unroll
    for (int i = 0; i < 4; ++i)
#pragma unroll
      for (int j = 0; j < 4; ++j) {
        int col = wcol * 64 + j * 16 + l15;
        float bz = bias[col];
#pragma unroll
        for (int r = 0; r < 4; ++r) {
          int row = wr * 64 + i * 16 + qd * 4 + r;   // row = t_l*8 + b
          tr[col * 136 + (row & 7) * 16 + (row >> 3)] = (__bf16)(acc[i][j][r] + bz);
        }
      }
    __syncthreads();
    int cbase = (mt >> 3) * 8;        // chunk c * 8
    int s0 = (mt & 7) * 16;           // s offset within chunk
#pragma unroll
    for (int it = 0; it < 4; ++it) {
      int p = it * 256 + tid;         // 1024 (d,b) pairs
      int d = p & 127, b = p >> 7;
      bf16x8 u0 = *(const bf16x8*)&tr[d * 136 + b * 16];
      bf16x8 u1 = *(const bf16x8*)&tr[d * 136 + b * 16 + 8];
      __bf16* dst = vt + ((long)(cbase + b) * 512 + nt * 128 + d) * 128 + s0;
      *(bf16x8*)dst = u0;
      *(bf16x8*)(dst + 8) = u1;
    }
    return;
  }

  const float* bias; bool sig = false;
  __bf16* dstb = nullptr; float* dstf = nullptr;
  if (nt == 4)      { bias = bk; dstb = kout; }
  else if (nt == 5) { bias = bq; dstb = qout; }
  else              { bias = ba; dstf = aout; sig = true; }

#pragma unroll
  for (int i = 0; i < 4; ++i)
#pragma unroll
    for (int j = 0; j < 4; ++j) {
      int col = wcol * 64 + j * 16 + l15;
      float bz = bias[col];
#pragma unroll
      for (int r = 0; r < 4; ++r) {
        int row = wr * 64 + i * 16 + qd * 4 + r;
        float z = acc[i][j][r] + bz;
        long addr = ((long)mt * 128 + row) * 128 + col;
        if (sig) dstf[addr] = 1.f / (1.f + __expf(-z));
        else     dstb[addr] = (__bf16)z;
      }
    }
}

// ---- scan_cp: cumprod; emits qb/kbs bf16 natural, kt transposed, cpend ----
// grid 128 (one block per (c,b)), 128 threads (n). Unroll-4 batched loads.
__global__ __launch_bounds__(128) void scan_cp(const float* __restrict__ a,
                                               const __bf16* __restrict__ k,
                                               const __bf16* __restrict__ q,
                                               __bf16* __restrict__ kbs,
                                               __bf16* __restrict__ qb,
                                               __bf16* __restrict__ kt,
                                               float* __restrict__ cpend) {
  int n = threadIdx.x;
  int blk = blockIdx.x;                 // c*8 + b
  int b = blk & 7, c = blk >> 3;
  long base = ((long)c * 1024 + b) * 128 + n;
  float cp = 1.f;
  __bf16 ktbuf[128];
  for (int t0 = 0; t0 < 128; t0 += 4) {
    float av[4], kv[4], qv[4];
#pragma unroll
    for (int u = 0; u < 4; ++u) {       // independent loads, batched in flight
      long off = base + (long)(t0 + u) * 1024;
      av[u] = a[off];
      kv[u] = (float)k[off];
      qv[u] = (float)q[off];
    }
#pragma unroll
    for (int u = 0; u < 4; ++u) {
      long off = base + (long)(t0 + u) * 1024;
      cp *= fmaxf(av[u], EPSV);
      float inv = 1.f / (cp + EPSV);
      float kk = kv[u] * inv;
      float qq = qv[u] * cp;
      __bf16 kh = (__bf16)kk;
      kbs[off] = kh;
      qb[off] = (__bf16)qq;
      ktbuf[t0 + u] = kh;
    }
  }
  cpend[blk * 128 + n] = cp;
  __bf16* dst = kt + ((long)(blk * 128 + n)) * 128;
#pragma unroll
  for (int i = 0; i < 16; ++i) {
    bf16x8 h;
#pragma unroll
    for (int j = 0; j < 8; ++j) h[j] = ktbuf[i * 8 + j];
    *(bf16x8*)(dst + i * 8) = h;
  }
}

// ---- gmm: Gt[d,n] = cpend[n] * sum_s vt[d,s]*kt[n,s].  grid 512 = cb*4+dt ----
__global__ __launch_bounds__(256) void gmm(const __bf16* __restrict__ vt,
                                           const __bf16* __restrict__ kt,
                                           const float* __restrict__ cpend,
                                           __bf16* __restrict__ Gt) {
  int tid = threadIdx.x, lane = tid & 63, wave = tid >> 6;
  int wr = wave >> 1, wc = wave & 1;
  int l15 = lane & 15, qd = lane >> 4;
  int cb = blockIdx.x >> 2, dt = blockIdx.x & 3;
  const __bf16* vbase = vt + ((long)cb * 512 + dt * 128) * 128;
  const __bf16* kbase = kt + (long)cb * 16384;
  f32x4 acc[4][4] = {};
#pragma unroll
  for (int kk = 0; kk < 4; ++kk) {
    int k0 = kk * 32;
    bf16x8 af[4], bfr[4];
#pragma unroll
    for (int i = 0; i < 4; ++i)
      af[i] = *(const bf16x8*)(vbase + (long)(wr * 64 + i * 16 + l15) * 128 + k0 + qd * 8);
#pragma unroll
    for (int j = 0; j < 4; ++j)
      bfr[j] = *(const bf16x8*)(kbase + (long)(wc * 64 + j * 16 + l15) * 128 + k0 + qd * 8);
#pragma unroll
    for (int i = 0; i < 4; ++i)
#pragma unroll
      for (int j = 0; j < 4; ++j)
        acc[i][j] = __builtin_amdgcn_mfma_f32_16x16x32_bf16(af[i], bfr[j], acc[i][j], 0, 0, 0);
  }
  float ce[4];
#pragma unroll
  for (int j = 0; j < 4; ++j) ce[j] = cpend[cb * 128 + wc * 64 + j * 16 + l15];
#pragma unroll
  for (int i = 0; i < 4; ++i)
#pragma unroll
    for (int j = 0; j < 4; ++j) {
      int col = wc * 64 + j * 16 + l15;
#pragma unroll
      for (int r = 0; r < 4; ++r) {
        int row = wr * 64 + i * 16 + qd * 4 + r;
        Gt[((long)cb * 512 + dt * 128 + row) * 128 + col] = (__bf16)(acc[i][j][r] * ce[j]);
      }
    }
}

// ---- scan_state: fp32 scan over chunks on Gt(bf16); emits St bf16 ----
__global__ __launch_bounds__(256) void scan_state(const __bf16* __restrict__ Gt,
                                                  const float* __restrict__ cpend,
                                                  __bf16* __restrict__ St) {
  long e = (long)blockIdx.x * 256 + threadIdx.x;  // 524288 = 8b*512d*128n
  int n = (int)(e & 127);
  int b = (int)(e >> 16);
  float S = 0.f;
#pragma unroll
  for (int c = 0; c < 16; ++c) {
    long idx = (long)c * 524288 + e;
    float g = (float)Gt[idx];
    St[idx] = (__bf16)S;
    S = g + S * cpend[(c * 8 + b) * 128 + n];
  }
}

// ---- ymm: y^T[d,t] = sum_s vt[d,s]*A[t,s] + sum_n St[d,n]*qb[t,n] ----
__global__ __launch_bounds__(256) void ymm(const __bf16* __restrict__ qb,
                                           const __bf16* __restrict__ kbs,
                                           const __bf16* __restrict__ vt,
                                           const __bf16* __restrict__ St,
                                           float* __restrict__ out) {
  __shared__ __bf16 A_lds[128 * 136];
  int tid = threadIdx.x, lane = tid & 63, wave = tid >> 6;
  int wr = wave >> 1, wc = wave & 1;
  int l15 = lane & 15, qd = lane >> 4;
  int cb = blockIdx.x >> 2, dt = blockIdx.x & 3;
  int c = cb >> 3, b = cb & 7;
  const __bf16* qbase = qb + ((long)c * 1024 + b) * 128;
  const __bf16* kbase = kbs + ((long)c * 1024 + b) * 128;

  {
    f32x4 accA[4][4] = {};
#pragma unroll
    for (int kk = 0; kk < 4; ++kk) {
      int k0 = kk * 32;
      bf16x8 af[4], bfr[4];
#pragma unroll
      for (int i = 0; i < 4; ++i)
        af[i] = *(const bf16x8*)(qbase + (long)(wr * 64 + i * 16 + l15) * 1024 + k0 + qd * 8);
#pragma unroll
      for (int j = 0; j < 4; ++j)
        bfr[j] = *(const bf16x8*)(kbase + (long)(wc * 64 + j * 16 + l15) * 1024 + k0 + qd * 8);
#pragma unroll
      for (int i = 0; i < 4; ++i)
#pragma unroll
        for (int j = 0; j < 4; ++j)
          accA[i][j] = __builtin_amdgcn_mfma_f32_16x16x32_bf16(af[i], bfr[j], accA[i][j], 0, 0, 0);
    }
#pragma unroll
    for (int i = 0; i < 4; ++i)
#pragma unroll
      for (int j = 0; j < 4; ++j) {
        int s = wc * 64 + j * 16 + l15;
#pragma unroll
        for (int r = 0; r < 4; ++r) {
          int t = wr * 64 + i * 16 + qd * 4 + r;
          A_lds[t * 136 + s] = (s <= t) ? (__bf16)accA[i][j][r] : (__bf16)0.f;
        }
      }
  }
  __syncthreads();

  f32x4 acc[4][4] = {};
  const __bf16* vbase = vt + ((long)cb * 512 + dt * 128) * 128;
  const __bf16* sbase = St + ((long)cb * 512 + dt * 128) * 128;
#pragma unroll
  for (int kk = 0; kk < 4; ++kk) {
    int k0 = kk * 32;
    bf16x8 af[4], bfr[4];
#pragma unroll
    for (int i = 0; i < 4; ++i)
      af[i] = *(const bf16x8*)(vbase + (long)(wr * 64 + i * 16 + l15) * 128 + k0 + qd * 8);
#pragma unroll
    for (int j = 0; j < 4; ++j)
      bfr[j] = *(const bf16x8*)&A_lds[(wc * 64 + j * 16 + l15) * 136 + k0 + qd * 8];
#pragma unroll
    for (int i = 0; i < 4; ++i)
#pragma unroll
      for (int j = 0; j < 4; ++j)
        acc[i][j] = __builtin_amdgcn_mfma_f32_16x16x32_bf16(af[i], bfr[j], acc[i][j], 0, 0, 0);
  }
#pragma unroll
  for (int kk = 0; kk < 4; ++kk) {
    int k0 = kk * 32;
    bf16x8 af[4], bfr[4];
#pragma unroll
    for (int i = 0; i < 4; ++i)
      af[i] = *(const bf16x8*)(sbase + (long)(wr * 64 + i * 16 + l15) * 128 + k0 + qd * 8);
#pragma unroll
    for (int j = 0; j < 4; ++j)
      bfr[j] = *(const bf16x8*)(qbase + (long)(wc * 64 + j * 16 + l15) * 1024 + k0 + qd * 8);
#pragma unroll
    for (int i = 0; i < 4; ++i)
#pragma unroll
      for (int j = 0; j < 4; ++j)
        acc[i][j] = __builtin_amdgcn_mfma_f32_16x16x32_bf16(af[i], bfr[j], acc[i][j], 0, 0, 0);
  }

#pragma unroll
  for (int i = 0; i < 4; ++i)
#pragma unroll
    for (int j = 0; j < 4; ++j) {
      int colt = wc * 64 + j * 16 + l15;
      long addr = ((long)(c * 128 + colt) * 8 + b) * 512 + dt * 128 + wr * 64 + i * 16 + qd * 4;
      *(float4*)(out + addr) = *(float4*)&acc[i][j];
    }
}

extern "C" void kernel_launch(void* const* d_in, const int* in_sizes, int n_in,
                              void* d_out, int out_size, void* d_ws, size_t ws_size,
                              hipStream_t stream) {
  const float* x  = (const float*)d_in[0];
  const float* Wv = (const float*)d_in[1];
  const float* bv = (const float*)d_in[2];
  const float* Wk = (const float*)d_in[3];
  const float* bk = (const float*)d_in[4];
  const float* Wq = (const float*)d_in[5];
  const float* bq = (const float*)d_in[6];
  const float* Wa = (const float*)d_in[7];
  const float* ba = (const float*)d_in[8];
  float* out = (float*)d_out;
  float* ws = (float*)d_ws;

  // float-unit offsets; total 20,168,704 fl = 80.7 MB
  float*  a_buf = ws;                          // 2,097,152 fl
  __bf16* qb    = (__bf16*)(ws + 2097152);     // 2,097,152 bf
  __bf16* kbs   = (__bf16*)(ws + 3145728);     // 2,097,152 bf
  __bf16* kt    = (__bf16*)(ws + 4194304);     // 2,097,152 bf
  __bf16* vt    = (__bf16*)(ws + 5242880);     // 8,388,608 bf
  __bf16* k_raw = (__bf16*)(ws + 9437184);     // 2,097,152 bf
  __bf16* q_raw = (__bf16*)(ws + 10485760);    // 2,097,152 bf
  __bf16* xb    = (__bf16*)(ws + 11534336);    // 8,388,608 bf
  __bf16* Wcat  = (__bf16*)(ws + 15728640);    // 458,752 bf
  __bf16* Gt    = xb;                          // overlay: xb dead after proj
  __bf16* St    = (__bf16*)(ws + 15958016);    // 8,388,608 bf
  float*  cpend = ws + 20152320;               // 16,384 fl

  conv_bf16<<<4096, 256, 0, stream>>>(x, xb);
  conv_w<<<224, 256, 0, stream>>>(Wv, Wk, Wq, Wa, Wcat);
  proj_mfma<<<dim3(128, 7), 256, 0, stream>>>(xb, Wcat, bv, bk, bq, ba,
                                              vt, k_raw, q_raw, a_buf);
  scan_cp<<<128, 128, 0, stream>>>(a_buf, k_raw, q_raw, kbs, qb, kt, cpend);
  gmm<<<512, 256, 0, stream>>>(vt, kt, cpend, Gt);
  scan_state<<<2048, 256, 0, stream>>>(Gt, cpend, St);
  ymm<<<512, 256, 0, stream>>>(qb, kbs, vt, St, out);
}